// Round 2
// baseline (326.550 us; speedup 1.0000x reference)
//
#include <hip/hip_runtime.h>

// Depthwise 4x4 binomial blur, fp32, separable ([1,3,3,1]^T [1,3,3,1])/64.
// x: (8, 64, 512, 512), pad (1,1,1,1), stride 1 -> out: (8, 64, 511, 511)

constexpr int H  = 512;
constexpr int W  = 512;
constexpr int OH = 511;
constexpr int OW = 511;
constexpr int BC = 8 * 64;

constexpr int TW = 64;        // output tile width  (1 col per lane)
constexpr int TH = 64;        // output tile height (16 rows per thread)
constexpr int SH = TH + 3;    // 67 staged input rows
constexpr int SF4 = 18;       // float4 per staged row: cols tx0-4 .. tx0+67
constexpr int SSTR = 76;      // LDS row stride in floats (76*4B % 16 == 0, %32 banks = 12)

__global__ __launch_bounds__(256, 4)
void blur_kernel(const float* __restrict__ in, float* __restrict__ out)
{
    __shared__ float s[SH * SSTR];   // 67*76*4 = 20368 B

    const int tx0 = blockIdx.x * TW;
    const int ty0 = blockIdx.y * TH;
    const int bc  = blockIdx.z;

    const float* __restrict__ inp  = in  + (size_t)bc * (H * W);
    float* __restrict__       outp = out + (size_t)bc * (OH * OW);

    const int tid = threadIdx.x;

    // ---- stage input tile into LDS as aligned float4 ----
    // LDS col l corresponds to input col (tx0 - 4 + l); every staged f4 is
    // either fully in-range or fully zero (W % 4 == 0, bases % 4 == 0).
    for (int idx = tid; idx < SH * SF4; idx += 256) {
        const int r   = idx / SF4;
        const int c   = idx - r * SF4;
        const int gy  = ty0 - 1 + r;
        const int gx0 = tx0 - 4 + 4 * c;
        float4 v = make_float4(0.f, 0.f, 0.f, 0.f);
        if ((unsigned)gy < (unsigned)H && (unsigned)gx0 <= (unsigned)(W - 4))
            v = *reinterpret_cast<const float4*>(&inp[(size_t)gy * W + gx0]);
        *reinterpret_cast<float4*>(&s[r * SSTR + 4 * c]) = v;
    }
    __syncthreads();

    // ---- compute: lane -> output col, each thread does 16 rows ----
    const int x  = tid & 63;          // output col within tile
    const int rb = (tid >> 6) * 16;   // base output row of this wave's strip

    // horizontal pass: h[j] for LDS rows rb .. rb+18
    // input cols needed for col x: tx0+x-1 .. tx0+x+2  ->  LDS l = x+3 .. x+6
    float h[19];
    #pragma unroll
    for (int j = 0; j < 19; ++j) {
        const float* row = &s[(rb + j) * SSTR + x + 3];
        const float a = row[0], b = row[1], c = row[2], d = row[3];
        h[j] = (a + d) + 3.0f * (b + c);
    }

    const int ox = tx0 + x;
    if (ox < OW) {
        #pragma unroll
        for (int k = 0; k < 16; ++k) {
            const int oy = ty0 + rb + k;
            if (oy < OH) {
                const float v = ((h[k] + h[k + 3]) + 3.0f * (h[k + 1] + h[k + 2]))
                                * 0.015625f;   // /64
                outp[(size_t)oy * OW + ox] = v;
            }
        }
    }
}

extern "C" void kernel_launch(void* const* d_in, const int* in_sizes, int n_in,
                              void* d_out, int out_size, void* d_ws, size_t ws_size,
                              hipStream_t stream)
{
    const float* x = (const float*)d_in[0];
    float* out = (float*)d_out;

    dim3 grid((OW + TW - 1) / TW,   // 8
              (OH + TH - 1) / TH,   // 8
              BC);                  // 512
    dim3 block(256);
    blur_kernel<<<grid, block, 0, stream>>>(x, out);
}

// Round 3
// 270.398 us; speedup vs baseline: 1.2077x; 1.2077x over previous
//
#include <hip/hip_runtime.h>

// Depthwise 4x4 binomial blur, fp32, separable ([1,3,3,1]^T [1,3,3,1])/64.
// x: (8, 64, 512, 512), pad (1,1,1,1), stride 1 -> out: (8, 64, 511, 511)
//
// Streaming, LDS-free: thread owns 4 output cols x 64-row strip; horizontal
// filter results of the trailing 3 input rows live in registers (h0..h2);
// two-row P/Q load pipeline keeps global loads in flight continuously.

constexpr int H  = 512;
constexpr int W  = 512;
constexpr int OH = 511;
constexpr int OW = 511;
constexpr int NPLANES = 8 * 64;

typedef float f4u __attribute__((ext_vector_type(4), aligned(4)));

struct Row { float4 A, B, C; };   // input cols cb-4..cb+7 of one row

__device__ __forceinline__ Row ldrow(const float* __restrict__ ip, int gy,
                                     int cb, bool aok, bool cok)
{
    Row r;
    r.A = make_float4(0.f, 0.f, 0.f, 0.f);
    r.B = r.A;
    r.C = r.A;
    if ((unsigned)gy < (unsigned)H) {          // wave-uniform (vertical pad)
        const float* p = ip + (size_t)gy * W + cb;
        r.B = *reinterpret_cast<const float4*>(p);
        if (aok) r.A = *reinterpret_cast<const float4*>(p - 4);  // left halo
        if (cok) r.C = *reinterpret_cast<const float4*>(p + 4);  // right halo
    }
    return r;
}

// horizontal pass for out cols cb..cb+3: h[j] = in[cb+j-1] + 3in[cb+j] + 3in[cb+j+1] + in[cb+j+2]
__device__ __forceinline__ float4 hp(const Row& r)
{
    float4 h;
    h.x = (r.A.w + r.B.z) + 3.f * (r.B.x + r.B.y);
    h.y = (r.B.x + r.B.w) + 3.f * (r.B.y + r.B.z);
    h.z = (r.B.y + r.C.x) + 3.f * (r.B.z + r.B.w);
    h.w = (r.B.z + r.C.y) + 3.f * (r.B.w + r.C.x);
    return h;
}

__device__ __forceinline__ float4 vcomb(const float4& h0, const float4& h1,
                                        const float4& h2, const float4& h3)
{
    float4 o;
    o.x = ((h0.x + h3.x) + 3.f * (h1.x + h2.x)) * 0.015625f;
    o.y = ((h0.y + h3.y) + 3.f * (h1.y + h2.y)) * 0.015625f;
    o.z = ((h0.z + h3.z) + 3.f * (h1.z + h2.z)) * 0.015625f;
    o.w = ((h0.w + h3.w) + 3.f * (h1.w + h2.w)) * 0.015625f;
    return o;
}

__device__ __forceinline__ void st(float* __restrict__ op, int oy, int cb,
                                   bool cok, const float4& o)
{
    float* p = op + (size_t)oy * OW + cb;
    if (cok) {
        *reinterpret_cast<f4u*>(p) = (f4u){o.x, o.y, o.z, o.w};  // 4B-aligned dwordx4
    } else {   // xt == 127: out col 511 doesn't exist
        p[0] = o.x; p[1] = o.y; p[2] = o.z;
    }
}

__global__ __launch_bounds__(256)
void blur_kernel(const float* __restrict__ in, float* __restrict__ out)
{
    const int tid   = threadIdx.x;
    const int xt    = tid & 127;        // col group: cols 4*xt .. 4*xt+3
    const int sub   = tid >> 7;         // 0/1: which 64-row sub-strip
    const int cb    = xt * 4;
    const int plane = blockIdx.x;
    const int ys    = blockIdx.y * 128 + sub * 64;
    const int ye    = min(ys + 64, OH);

    const float* __restrict__ ip = in  + (size_t)plane * (H * W);
    float*       __restrict__ op = out + (size_t)plane * (OH * OW);

    const bool aok = (xt > 0);
    const bool cok = (xt < 127);

    // prologue: issue 5 rows of loads before any use
    Row r0 = ldrow(ip, ys - 1, cb, aok, cok);
    Row r1 = ldrow(ip, ys,     cb, aok, cok);
    Row r2 = ldrow(ip, ys + 1, cb, aok, cok);
    Row P  = ldrow(ip, ys + 2, cb, aok, cok);
    Row Q  = ldrow(ip, ys + 3, cb, aok, cok);

    float4 h0 = hp(r0);
    float4 h1 = hp(r1);
    float4 h2 = hp(r2);

    int oy = ys;
    while (oy + 1 < ye) {
        float4 h3 = hp(P);
        st(op, oy, cb, cok, vcomb(h0, h1, h2, h3));
        P = ldrow(ip, oy + 4, cb, aok, cok);      // refill P, Q still in flight

        float4 h4 = hp(Q);
        st(op, oy + 1, cb, cok, vcomb(h1, h2, h3, h4));
        Q = ldrow(ip, oy + 5, cb, aok, cok);      // refill Q, P in flight

        h0 = h2; h1 = h3; h2 = h4;
        oy += 2;
    }
    if (oy < ye) {                                 // odd tail (last strip: 63 rows)
        float4 h3 = hp(P);
        st(op, oy, cb, cok, vcomb(h0, h1, h2, h3));
    }
}

extern "C" void kernel_launch(void* const* d_in, const int* in_sizes, int n_in,
                              void* d_out, int out_size, void* d_ws, size_t ws_size,
                              hipStream_t stream)
{
    const float* x = (const float*)d_in[0];
    float* out = (float*)d_out;

    dim3 grid(NPLANES, 4);   // 512 planes x 4 block-strips (2 sub-strips each)
    dim3 block(256);
    blur_kernel<<<grid, block, 0, stream>>>(x, out);
}

// Round 4
// 251.587 us; speedup vs baseline: 1.2980x; 1.0748x over previous
//
#include <hip/hip_runtime.h>

// Depthwise 4x4 binomial blur, fp32, separable ([1,3,3,1]^T [1,3,3,1])/64.
// x: (8, 64, 512, 512), pad (1,1,1,1) -> out: (8, 64, 511, 511)
//
// One wave owns a full 512-wide row strip (8 cols/lane). Horizontal halo via
// intra-wave shuffles (image edges are zero-pad -> no halo loads at all).
// Vertical reuse in registers; 4-row deep load pipeline. No LDS, no barriers.

constexpr int H  = 512;
constexpr int W  = 512;
constexpr int OH = 511;
constexpr int OW = 511;
constexpr int NPLANES = 8 * 64;

typedef float f4u __attribute__((ext_vector_type(4), aligned(4)));

struct H8 { float v[8]; };
struct R2 { float4 b0, b1; };   // input cols 8l..8l+3, 8l+4..8l+7

__device__ __forceinline__ R2 ldrow(const float* __restrict__ ip, int gy, int cb)
{
    R2 r;
    r.b0 = make_float4(0.f, 0.f, 0.f, 0.f);
    r.b1 = r.b0;
    if ((unsigned)gy < (unsigned)H) {      // wave-uniform vertical pad
        const float* p = ip + (size_t)gy * W + cb;
        r.b0 = *reinterpret_cast<const float4*>(p);
        r.b1 = *reinterpret_cast<const float4*>(p + 4);
    }
    return r;
}

// horizontal [1,3,3,1] at cols cb-1..cb+9 -> h[0..7] for out cols cb..cb+7
__device__ __forceinline__ H8 hp8(const R2& r, bool l0, bool l63)
{
    float L  = __shfl_up(r.b1.w, 1);     // col cb-1 from lane-1
    float RX = __shfl_down(r.b0.x, 1);   // col cb+8 from lane+1
    float RY = __shfl_down(r.b0.y, 1);   // col cb+9 from lane+1
    L  = l0  ? 0.f : L;                  // image left edge zero-pad
    RX = l63 ? 0.f : RX;                 // image right edge zero-pad
    RY = l63 ? 0.f : RY;
    H8 h;
    h.v[0] = (L       + r.b0.z) + 3.f * (r.b0.x + r.b0.y);
    h.v[1] = (r.b0.x  + r.b0.w) + 3.f * (r.b0.y + r.b0.z);
    h.v[2] = (r.b0.y  + r.b1.x) + 3.f * (r.b0.z + r.b0.w);
    h.v[3] = (r.b0.z  + r.b1.y) + 3.f * (r.b0.w + r.b1.x);
    h.v[4] = (r.b0.w  + r.b1.z) + 3.f * (r.b1.x + r.b1.y);
    h.v[5] = (r.b1.x  + r.b1.w) + 3.f * (r.b1.y + r.b1.z);
    h.v[6] = (r.b1.y  + RX)     + 3.f * (r.b1.z + r.b1.w);
    h.v[7] = (r.b1.z  + RY)     + 3.f * (r.b1.w + RX);
    return h;
}

// vertical [1,3,3,1] combine + store 8 cols. OW=511: lane 63's upper half is
// stored as an overlapping shifted dwordx4 at cols 507..510 (col 507 is
// double-written with the identical value) -> no divergence, no scalar tail.
__device__ __forceinline__ void vst(float* __restrict__ op, int oy, int cb, bool l63,
                                    const H8& a, const H8& b, const H8& c, const H8& d)
{
    if (oy >= OH) return;                // wave-uniform
    float o[8];
    #pragma unroll
    for (int j = 0; j < 8; ++j)
        o[j] = ((a.v[j] + d.v[j]) + 3.f * (b.v[j] + c.v[j])) * 0.015625f;
    float* p = op + (size_t)oy * OW + cb;
    *reinterpret_cast<f4u*>(p) = (f4u){o[0], o[1], o[2], o[3]};
    f4u s2 = { l63 ? o[3] : o[4], l63 ? o[4] : o[5],
               l63 ? o[5] : o[6], l63 ? o[6] : o[7] };
    *reinterpret_cast<f4u*>(p + (l63 ? 3 : 4)) = s2;
}

__global__ __launch_bounds__(256)
void blur_kernel(const float* __restrict__ in, float* __restrict__ out)
{
    const int  tid  = threadIdx.x;
    const int  lane = tid & 63;
    const int  wv   = tid >> 6;          // wave 0..3 -> 32-row strip each
    const bool l0   = (lane == 0), l63 = (lane == 63);
    const int  cb   = lane * 8;

    const int plane = blockIdx.x;
    const int ys    = blockIdx.y * 128 + wv * 32;

    const float* __restrict__ ip = in  + (size_t)plane * (H * W);
    float*       __restrict__ op = out + (size_t)plane * (OH * OW);

    // prologue: 7 rows of loads in flight before first use
    R2 r0 = ldrow(ip, ys - 1, cb);
    R2 r1 = ldrow(ip, ys,     cb);
    R2 r2 = ldrow(ip, ys + 1, cb);
    R2 P0 = ldrow(ip, ys + 2, cb);
    R2 P1 = ldrow(ip, ys + 3, cb);
    R2 P2 = ldrow(ip, ys + 4, cb);
    R2 P3 = ldrow(ip, ys + 5, cb);

    H8 hA = hp8(r0, l0, l63);
    H8 hB = hp8(r1, l0, l63);
    H8 hC = hp8(r2, l0, l63);

    int oy = ys;
    #pragma unroll 1
    for (; oy < ys + 28; oy += 4) {
        H8 h3 = hp8(P0, l0, l63); vst(op, oy,     cb, l63, hA, hB, hC, h3); P0 = ldrow(ip, oy + 6, cb);
        H8 h4 = hp8(P1, l0, l63); vst(op, oy + 1, cb, l63, hB, hC, h3, h4); P1 = ldrow(ip, oy + 7, cb);
        H8 h5 = hp8(P2, l0, l63); vst(op, oy + 2, cb, l63, hC, h3, h4, h5); P2 = ldrow(ip, oy + 8, cb);
        H8 h6 = hp8(P3, l0, l63); vst(op, oy + 3, cb, l63, h3, h4, h5, h6); P3 = ldrow(ip, oy + 9, cb);
        hA = h4; hB = h5; hC = h6;
    }
    // final 4 rows: no refills (avoids 4 wasted row-loads per strip)
    {
        H8 h3 = hp8(P0, l0, l63); vst(op, oy,     cb, l63, hA, hB, hC, h3);
        H8 h4 = hp8(P1, l0, l63); vst(op, oy + 1, cb, l63, hB, hC, h3, h4);
        H8 h5 = hp8(P2, l0, l63); vst(op, oy + 2, cb, l63, hC, h3, h4, h5);
        H8 h6 = hp8(P3, l0, l63); vst(op, oy + 3, cb, l63, h3, h4, h5, h6);
    }
}

extern "C" void kernel_launch(void* const* d_in, const int* in_sizes, int n_in,
                              void* d_out, int out_size, void* d_ws, size_t ws_size,
                              hipStream_t stream)
{
    const float* x = (const float*)d_in[0];
    float* out = (float*)d_out;

    dim3 grid(NPLANES, 4);   // 512 planes x 4 wave-strip groups (128 rows each)
    dim3 block(256);
    blur_kernel<<<grid, block, 0, stream>>>(x, out);
}

// Round 5
// 249.630 us; speedup vs baseline: 1.3081x; 1.0078x over previous
//
#include <hip/hip_runtime.h>

// Depthwise 4x4 binomial blur, fp32, separable ([1,3,3,1]^T [1,3,3,1])/64.
// x: (8, 64, 512, 512), pad (1,1,1,1) -> out: (8, 64, 511, 511)
//
// One wave owns a full 512-wide row strip (8 cols/lane), 32 rows per wave.
// Horizontal halo via intra-wave shuffles (image edges zero-pad -> no halo
// loads). Vertical reuse in registers. 6-row-deep register ring (P0..P5,
// unroll-6 -> mov-free rotation) keeps ~660 cy of load lookahead per wave.
// No LDS, no barriers.

constexpr int H  = 512;
constexpr int W  = 512;
constexpr int OH = 511;
constexpr int OW = 511;
constexpr int NPLANES = 8 * 64;

typedef float f4u __attribute__((ext_vector_type(4), aligned(4)));

struct H8 { float v[8]; };
struct R2 { float4 b0, b1; };   // input cols 8l..8l+3, 8l+4..8l+7

__device__ __forceinline__ R2 ldrow(const float* __restrict__ ip, int gy, int cb)
{
    R2 r;
    r.b0 = make_float4(0.f, 0.f, 0.f, 0.f);
    r.b1 = r.b0;
    if ((unsigned)gy < (unsigned)H) {      // wave-uniform vertical pad
        const float* p = ip + (size_t)gy * W + cb;
        r.b0 = *reinterpret_cast<const float4*>(p);
        r.b1 = *reinterpret_cast<const float4*>(p + 4);
    }
    return r;
}

// horizontal [1,3,3,1] at cols cb-1..cb+9 -> h[0..7] for out cols cb..cb+7
__device__ __forceinline__ H8 hp8(const R2& r, bool l0, bool l63)
{
    float L  = __shfl_up(r.b1.w, 1);     // col cb-1 from lane-1
    float RX = __shfl_down(r.b0.x, 1);   // col cb+8 from lane+1
    float RY = __shfl_down(r.b0.y, 1);   // col cb+9 from lane+1
    L  = l0  ? 0.f : L;
    RX = l63 ? 0.f : RX;
    RY = l63 ? 0.f : RY;
    H8 h;
    h.v[0] = (L       + r.b0.z) + 3.f * (r.b0.x + r.b0.y);
    h.v[1] = (r.b0.x  + r.b0.w) + 3.f * (r.b0.y + r.b0.z);
    h.v[2] = (r.b0.y  + r.b1.x) + 3.f * (r.b0.z + r.b0.w);
    h.v[3] = (r.b0.z  + r.b1.y) + 3.f * (r.b0.w + r.b1.x);
    h.v[4] = (r.b0.w  + r.b1.z) + 3.f * (r.b1.x + r.b1.y);
    h.v[5] = (r.b1.x  + r.b1.w) + 3.f * (r.b1.y + r.b1.z);
    h.v[6] = (r.b1.y  + RX)     + 3.f * (r.b1.z + r.b1.w);
    h.v[7] = (r.b1.z  + RY)     + 3.f * (r.b1.w + RX);
    return h;
}

// vertical [1,3,3,1] combine + store 8 cols. OW=511: lane 63 stores an
// overlapping shifted dwordx4 (col 507 double-written, same value).
__device__ __forceinline__ void vst(float* __restrict__ op, int oy, int cb, bool l63,
                                    const H8& a, const H8& b, const H8& c, const H8& d)
{
    if (oy < OH) {                       // wave-uniform (only masks oy==511)
        float o[8];
        #pragma unroll
        for (int j = 0; j < 8; ++j)
            o[j] = ((a.v[j] + d.v[j]) + 3.f * (b.v[j] + c.v[j])) * 0.015625f;
        float* p = op + (size_t)oy * OW + cb;
        *reinterpret_cast<f4u*>(p) = (f4u){o[0], o[1], o[2], o[3]};
        f4u s2 = { l63 ? o[3] : o[4], l63 ? o[4] : o[5],
                   l63 ? o[5] : o[6], l63 ? o[6] : o[7] };
        *reinterpret_cast<f4u*>(p + (l63 ? 3 : 4)) = s2;
    }
}

__global__ __launch_bounds__(256)
void blur_kernel(const float* __restrict__ in, float* __restrict__ out)
{
    const int  tid  = threadIdx.x;
    const int  lane = tid & 63;
    const int  wv   = tid >> 6;
    const bool l0   = (lane == 0), l63 = (lane == 63);
    const int  cb   = lane * 8;

    const int plane = blockIdx.x;
    const int ys    = blockIdx.y * 128 + wv * 32;   // 32-row strip per wave

    const float* __restrict__ ip = in  + (size_t)plane * (H * W);
    float*       __restrict__ op = out + (size_t)plane * (OH * OW);

    // prologue: 9 rows of loads in flight before first use
    R2 r0 = ldrow(ip, ys - 1, cb);
    R2 r1 = ldrow(ip, ys,     cb);
    R2 r2 = ldrow(ip, ys + 1, cb);
    R2 P0 = ldrow(ip, ys + 2, cb);
    R2 P1 = ldrow(ip, ys + 3, cb);
    R2 P2 = ldrow(ip, ys + 4, cb);
    R2 P3 = ldrow(ip, ys + 5, cb);
    R2 P4 = ldrow(ip, ys + 6, cb);
    R2 P5 = ldrow(ip, ys + 7, cb);

    H8 hA = hp8(r0, l0, l63);
    H8 hB = hp8(r1, l0, l63);
    H8 hC = hp8(r2, l0, l63);

    // main: 4 trips x 6 rows; ring depth 6 -> refill row = consume row + 6
    int i = 0;
    #pragma unroll 1
    for (int t = 0; t < 4; ++t, i += 6) {
        H8 h3;
        h3 = hp8(P0, l0, l63); vst(op, ys + i + 0, cb, l63, hA, hB, hC, h3); P0 = ldrow(ip, ys + i + 8,  cb); hA = hB; hB = hC; hC = h3;
        h3 = hp8(P1, l0, l63); vst(op, ys + i + 1, cb, l63, hA, hB, hC, h3); P1 = ldrow(ip, ys + i + 9,  cb); hA = hB; hB = hC; hC = h3;
        h3 = hp8(P2, l0, l63); vst(op, ys + i + 2, cb, l63, hA, hB, hC, h3); P2 = ldrow(ip, ys + i + 10, cb); hA = hB; hB = hC; hC = h3;
        h3 = hp8(P3, l0, l63); vst(op, ys + i + 3, cb, l63, hA, hB, hC, h3); P3 = ldrow(ip, ys + i + 11, cb); hA = hB; hB = hC; hC = h3;
        h3 = hp8(P4, l0, l63); vst(op, ys + i + 4, cb, l63, hA, hB, hC, h3); P4 = ldrow(ip, ys + i + 12, cb); hA = hB; hB = hC; hC = h3;
        h3 = hp8(P5, l0, l63); vst(op, ys + i + 5, cb, l63, hA, hB, hC, h3); P5 = ldrow(ip, ys + i + 13, cb); hA = hB; hB = hC; hC = h3;
    }

    // tail: i == 24. Last two input rows issued first (6 rows of cover).
    R2 Q0 = ldrow(ip, ys + 32, cb);
    R2 Q1 = ldrow(ip, ys + 33, cb);
    {
        H8 h3;
        h3 = hp8(P0, l0, l63); vst(op, ys + 24, cb, l63, hA, hB, hC, h3); hA = hB; hB = hC; hC = h3;
        h3 = hp8(P1, l0, l63); vst(op, ys + 25, cb, l63, hA, hB, hC, h3); hA = hB; hB = hC; hC = h3;
        h3 = hp8(P2, l0, l63); vst(op, ys + 26, cb, l63, hA, hB, hC, h3); hA = hB; hB = hC; hC = h3;
        h3 = hp8(P3, l0, l63); vst(op, ys + 27, cb, l63, hA, hB, hC, h3); hA = hB; hB = hC; hC = h3;
        h3 = hp8(P4, l0, l63); vst(op, ys + 28, cb, l63, hA, hB, hC, h3); hA = hB; hB = hC; hC = h3;
        h3 = hp8(P5, l0, l63); vst(op, ys + 29, cb, l63, hA, hB, hC, h3); hA = hB; hB = hC; hC = h3;
        h3 = hp8(Q0, l0, l63); vst(op, ys + 30, cb, l63, hA, hB, hC, h3); hA = hB; hB = hC; hC = h3;
        h3 = hp8(Q1, l0, l63); vst(op, ys + 31, cb, l63, hA, hB, hC, h3);
    }
}

extern "C" void kernel_launch(void* const* d_in, const int* in_sizes, int n_in,
                              void* d_out, int out_size, void* d_ws, size_t ws_size,
                              hipStream_t stream)
{
    const float* x = (const float*)d_in[0];
    float* out = (float*)d_out;

    dim3 grid(NPLANES, 4);   // 512 planes x 4 wave-strip groups (128 rows each)
    dim3 block(256);
    blur_kernel<<<grid, block, 0, stream>>>(x, out);
}

// Round 6
// 236.356 us; speedup vs baseline: 1.3816x; 1.0562x over previous
//
#include <hip/hip_runtime.h>

// Depthwise 4x4 binomial blur, fp32, separable ([1,3,3,1]^T [1,3,3,1])/64.
// x: (8, 64, 512, 512), pad (1,1,1,1) -> out: (8, 64, 511, 511)
//
// One wave owns a full 512-wide x 128-row strip (8 cols/lane): 512 blocks
// (1 plane each, 2 blocks/CU), 2048 long sequential streams instead of 8192
// scattered ones -> better DRAM page locality. Horizontal halo via intra-wave
// shuffles; vertical reuse in registers; 6-row register ring. No LDS/barriers.

constexpr int H  = 512;
constexpr int W  = 512;
constexpr int OH = 511;
constexpr int OW = 511;
constexpr int NPLANES = 8 * 64;

typedef float f4u __attribute__((ext_vector_type(4), aligned(4)));

struct H8 { float v[8]; };
struct R2 { float4 b0, b1; };   // input cols 8l..8l+3, 8l+4..8l+7

__device__ __forceinline__ R2 ldrow(const float* __restrict__ ip, int gy, int cb)
{
    R2 r;
    r.b0 = make_float4(0.f, 0.f, 0.f, 0.f);
    r.b1 = r.b0;
    if ((unsigned)gy < (unsigned)H) {      // wave-uniform vertical pad
        const float* p = ip + (size_t)gy * W + cb;
        r.b0 = *reinterpret_cast<const float4*>(p);
        r.b1 = *reinterpret_cast<const float4*>(p + 4);
    }
    return r;
}

// horizontal [1,3,3,1] at cols cb-1..cb+9 -> h[0..7] for out cols cb..cb+7
__device__ __forceinline__ H8 hp8(const R2& r, bool l0, bool l63)
{
    float L  = __shfl_up(r.b1.w, 1);     // col cb-1 from lane-1
    float RX = __shfl_down(r.b0.x, 1);   // col cb+8 from lane+1
    float RY = __shfl_down(r.b0.y, 1);   // col cb+9 from lane+1
    L  = l0  ? 0.f : L;
    RX = l63 ? 0.f : RX;
    RY = l63 ? 0.f : RY;
    H8 h;
    h.v[0] = (L       + r.b0.z) + 3.f * (r.b0.x + r.b0.y);
    h.v[1] = (r.b0.x  + r.b0.w) + 3.f * (r.b0.y + r.b0.z);
    h.v[2] = (r.b0.y  + r.b1.x) + 3.f * (r.b0.z + r.b0.w);
    h.v[3] = (r.b0.z  + r.b1.y) + 3.f * (r.b0.w + r.b1.x);
    h.v[4] = (r.b0.w  + r.b1.z) + 3.f * (r.b1.x + r.b1.y);
    h.v[5] = (r.b1.x  + r.b1.w) + 3.f * (r.b1.y + r.b1.z);
    h.v[6] = (r.b1.y  + RX)     + 3.f * (r.b1.z + r.b1.w);
    h.v[7] = (r.b1.z  + RY)     + 3.f * (r.b1.w + RX);
    return h;
}

// vertical [1,3,3,1] combine + store 8 cols. OW=511: lane 63 stores an
// overlapping shifted dwordx4 (col 507 double-written, same value).
__device__ __forceinline__ void vst(float* __restrict__ op, int oy, int cb, bool l63,
                                    const H8& a, const H8& b, const H8& c, const H8& d)
{
    if (oy < OH) {                       // wave-uniform (only masks oy==511)
        float o[8];
        #pragma unroll
        for (int j = 0; j < 8; ++j)
            o[j] = ((a.v[j] + d.v[j]) + 3.f * (b.v[j] + c.v[j])) * 0.015625f;
        float* p = op + (size_t)oy * OW + cb;
        *reinterpret_cast<f4u*>(p) = (f4u){o[0], o[1], o[2], o[3]};
        f4u s2 = { l63 ? o[3] : o[4], l63 ? o[4] : o[5],
                   l63 ? o[5] : o[6], l63 ? o[6] : o[7] };
        *reinterpret_cast<f4u*>(p + (l63 ? 3 : 4)) = s2;
    }
}

__global__ __launch_bounds__(256)
void blur_kernel(const float* __restrict__ in, float* __restrict__ out)
{
    const int  tid  = threadIdx.x;
    const int  lane = tid & 63;
    const int  wv   = tid >> 6;
    const bool l0   = (lane == 0), l63 = (lane == 63);
    const int  cb   = lane * 8;

    const int plane = blockIdx.x;
    const int ys    = wv * 128;          // 128-row strip per wave

    const float* __restrict__ ip = in  + (size_t)plane * (H * W);
    float*       __restrict__ op = out + (size_t)plane * (OH * OW);

    // prologue: 9 rows of loads in flight before first use
    R2 r0 = ldrow(ip, ys - 1, cb);
    R2 r1 = ldrow(ip, ys,     cb);
    R2 r2 = ldrow(ip, ys + 1, cb);
    R2 P0 = ldrow(ip, ys + 2, cb);
    R2 P1 = ldrow(ip, ys + 3, cb);
    R2 P2 = ldrow(ip, ys + 4, cb);
    R2 P3 = ldrow(ip, ys + 5, cb);
    R2 P4 = ldrow(ip, ys + 6, cb);
    R2 P5 = ldrow(ip, ys + 7, cb);

    H8 hA = hp8(r0, l0, l63);
    H8 hB = hp8(r1, l0, l63);
    H8 hC = hp8(r2, l0, l63);

    // main: 20 trips x 6 rows (120 rows); refill row = consume row + 6
    int i = 0;
    #pragma unroll 1
    for (int t = 0; t < 20; ++t, i += 6) {
        H8 h3;
        h3 = hp8(P0, l0, l63); vst(op, ys + i + 0, cb, l63, hA, hB, hC, h3); P0 = ldrow(ip, ys + i + 8,  cb); hA = hB; hB = hC; hC = h3;
        h3 = hp8(P1, l0, l63); vst(op, ys + i + 1, cb, l63, hA, hB, hC, h3); P1 = ldrow(ip, ys + i + 9,  cb); hA = hB; hB = hC; hC = h3;
        h3 = hp8(P2, l0, l63); vst(op, ys + i + 2, cb, l63, hA, hB, hC, h3); P2 = ldrow(ip, ys + i + 10, cb); hA = hB; hB = hC; hC = h3;
        h3 = hp8(P3, l0, l63); vst(op, ys + i + 3, cb, l63, hA, hB, hC, h3); P3 = ldrow(ip, ys + i + 11, cb); hA = hB; hB = hC; hC = h3;
        h3 = hp8(P4, l0, l63); vst(op, ys + i + 4, cb, l63, hA, hB, hC, h3); P4 = ldrow(ip, ys + i + 12, cb); hA = hB; hB = hC; hC = h3;
        h3 = hp8(P5, l0, l63); vst(op, ys + i + 5, cb, l63, hA, hB, hC, h3); P5 = ldrow(ip, ys + i + 13, cb); hA = hB; hB = hC; hC = h3;
    }

    // tail: i == 120. Last two input rows issued first (6 rows of cover).
    R2 Q0 = ldrow(ip, ys + 128, cb);
    R2 Q1 = ldrow(ip, ys + 129, cb);
    {
        H8 h3;
        h3 = hp8(P0, l0, l63); vst(op, ys + 120, cb, l63, hA, hB, hC, h3); hA = hB; hB = hC; hC = h3;
        h3 = hp8(P1, l0, l63); vst(op, ys + 121, cb, l63, hA, hB, hC, h3); hA = hB; hB = hC; hC = h3;
        h3 = hp8(P2, l0, l63); vst(op, ys + 122, cb, l63, hA, hB, hC, h3); hA = hB; hB = hC; hC = h3;
        h3 = hp8(P3, l0, l63); vst(op, ys + 123, cb, l63, hA, hB, hC, h3); hA = hB; hB = hC; hC = h3;
        h3 = hp8(P4, l0, l63); vst(op, ys + 124, cb, l63, hA, hB, hC, h3); hA = hB; hB = hC; hC = h3;
        h3 = hp8(P5, l0, l63); vst(op, ys + 125, cb, l63, hA, hB, hC, h3); hA = hB; hB = hC; hC = h3;
        h3 = hp8(Q0, l0, l63); vst(op, ys + 126, cb, l63, hA, hB, hC, h3); hA = hB; hB = hC; hC = h3;
        h3 = hp8(Q1, l0, l63); vst(op, ys + 127, cb, l63, hA, hB, hC, h3);
    }
}

extern "C" void kernel_launch(void* const* d_in, const int* in_sizes, int n_in,
                              void* d_out, int out_size, void* d_ws, size_t ws_size,
                              hipStream_t stream)
{
    const float* x = (const float*)d_in[0];
    float* out = (float*)d_out;

    dim3 grid(NPLANES);   // 512 blocks: 1 plane each, 4 waves x 128-row strips
    dim3 block(256);
    blur_kernel<<<grid, block, 0, stream>>>(x, out);
}